// Round 9
// baseline (245.793 us; speedup 1.0000x reference)
//
#include <hip/hip_runtime.h>
#include <hip/hip_bf16.h>
#include <cstdint>
#include <cstddef>

// Problem constants
#define D_DIM 16384   // random feature dim
#define S_DIM 4096    // n_states
#define A_DIM 512     // n_actions
#define K_DIM 128     // state_dim
#define B_DIM 16      // batch
#define CH    8       // chunks (of 64 kc rows) per fused block

#define INV2PI 0.15915494309189535f

typedef float f32x4 __attribute__((ext_vector_type(4)));
typedef short s16x8 __attribute__((ext_vector_type(8)));
typedef unsigned short u16;
typedef unsigned int   u32;

__device__ __forceinline__ u16 bf16bits(float x) {
    return __builtin_bit_cast(u16, (__bf16)x);
}
__device__ __forceinline__ s16x8 frag_cast(uint4 u) {
    return __builtin_bit_cast(s16x8, u);
}
// D.lo = bf16(lo), D.hi = bf16(hi)
__device__ __forceinline__ u32 cvt_pk_bf16(float lo, float hi) {
    u32 r;
    asm("v_cvt_pk_bf16_f32 %0, %1, %2" : "=v"(r) : "v"(lo), "v"(hi));
    return r;
}
// LDS 16B-chunk XOR swizzle (balanced: every bank serves exactly 8 u32 per
// ds_read_b128). Applied on BOTH the staging source and the read (rule #21).
__device__ __forceinline__ int sigma(int row) {
    return (row & 7) ^ ((row >> 1) & 4);
}
// async global->LDS 16B: LDS dest = wave-uniform base + lane*16 (HW rule)
__device__ __forceinline__ void g2l16(const u32* g, u32* l) {
    __builtin_amdgcn_global_load_lds((const __attribute__((address_space(1))) u32*)g,
                                     (__attribute__((address_space(3))) u32*)l, 16, 0, 0);
}

// ---------------------------------------------------------------------------
// Prep: W*(1/2pi) -> bf16 [D][128]; Q -> QT bf16 [S][128];
// obs -> packed bf16 B-frag layout obsP[(s>>3)][b][s&7]
// ---------------------------------------------------------------------------
__global__ void prep_kernel(const float* __restrict__ W, const float* __restrict__ Q,
                            const float* __restrict__ obs,
                            u16* __restrict__ Wb, u16* __restrict__ QT, u16* __restrict__ obsP)
{
    const int i0 = blockIdx.x * 256 + threadIdx.x;
    const int stride = gridDim.x * 256;
    const float4* wp = (const float4*)W;
    for (int i = i0; i < D_DIM * 16; i += stride) {
        float4 a = wp[2 * i], b = wp[2 * i + 1];
        uint4 o;
        o.x = cvt_pk_bf16(a.x * INV2PI, a.y * INV2PI);
        o.y = cvt_pk_bf16(a.z * INV2PI, a.w * INV2PI);
        o.z = cvt_pk_bf16(b.x * INV2PI, b.y * INV2PI);
        o.w = cvt_pk_bf16(b.z * INV2PI, b.w * INV2PI);
        ((uint4*)Wb)[i] = o;
    }
    for (int i = i0; i < S_DIM * 16; i += stride) {
        const int s = i >> 4, kc = i & 15;
        float q[8];
        #pragma unroll
        for (int j = 0; j < 8; ++j) q[j] = Q[(size_t)(kc * 8 + j) * S_DIM + s];
        uint4 o;
        o.x = cvt_pk_bf16(q[0], q[1]);
        o.y = cvt_pk_bf16(q[2], q[3]);
        o.z = cvt_pk_bf16(q[4], q[5]);
        o.w = cvt_pk_bf16(q[6], q[7]);
        ((uint4*)QT)[s * 16 + kc] = o;
    }
    for (int i = i0; i < B_DIM * S_DIM; i += stride) {
        int b = i >> 12, s = i & 4095;
        obsP[((s >> 3) << 7) + (b << 3) + (s & 7)] = bf16bits(obs[i]);
    }
}

// v[k][b] = sum_a V[k][a] * action[b][a]
__global__ void kv_kernel(const float* __restrict__ V, const float* __restrict__ act,
                          float* __restrict__ v)
{
    const int t = threadIdx.x;
    const int out = blockIdx.x * 32 + (t >> 3);
    const int part = t & 7;
    const int k = out >> 4, b = out & 15;
    const float4* vp = (const float4*)(V + (size_t)k * A_DIM);
    const float4* ap = (const float4*)(act + (size_t)b * A_DIM);
    float s = 0.f;
    #pragma unroll
    for (int q = part * 16; q < part * 16 + 16; ++q) {
        float4 x = vp[q], y = ap[q];
        s += x.x * y.x + x.y * y.y + x.z * y.z + x.w * y.w;
    }
    s += __shfl_xor(s, 1, 64);
    s += __shfl_xor(s, 2, 64);
    s += __shfl_xor(s, 4, 64);
    if (part == 0) v[out] = s;
}

// phi_v[d][b] = exp(i * (W@v)[d][b]) / 128   (accurate libm trig)
__global__ void phiv_kernel(const float* __restrict__ W, const float* __restrict__ v,
                            float* __restrict__ pvr, float* __restrict__ pvi)
{
    __shared__ float sv[K_DIM * 16];
    const int tid = threadIdx.x;
    for (int j = tid; j < K_DIM * 16; j += 256) sv[j] = v[j];
    __syncthreads();
    const int i = blockIdx.x * 256 + tid;
    const int d = i >> 4, b = i & 15;
    const float4* wp = (const float4*)(W + (size_t)d * K_DIM);
    float z = 0.f;
    #pragma unroll 8
    for (int q = 0; q < 32; ++q) {
        float4 w4 = wp[q];
        z += w4.x * sv[(4 * q + 0) * 16 + b] + w4.y * sv[(4 * q + 1) * 16 + b]
           + w4.z * sv[(4 * q + 2) * 16 + b] + w4.w * sv[(4 * q + 3) * 16 + b];
    }
    pvr[i] = cosf(z) * 0.0078125f;
    pvi[i] = sinf(z) * 0.0078125f;
}

// ---------------------------------------------------------------------------
// Fused phi-GEMM pass (R6-best structure), CH=8 chunks of 64 kc rows.
// Block: 64 M-rows, 4 waves = (wm in 2) x (wk in 2). Chunk staged to LDS
// (16 KB, double-buffered = 32 KB) via async global_load_lds.
// Wave computes m-half (2 tiles, P1 in regs) x kc-half (2 T-tiles, rowperm'd
// so z's C-frag IS the outer MFMA A-frag). Cross-wk reduction via LDS epilogue.
//  MODE 0: out1 = cos@y1 ; out2 = sin@y1   (A, C; [m][b] partials)
//  MODE 1: out1 = cos@y1 + sin@y2          (B, D; [b][m] partials)
// launch_bounds(256,5): 5 blocks/CU (LDS 160 KB exactly), VGPR cap 102.
// ---------------------------------------------------------------------------
template<int MODE>
__global__ __launch_bounds__(256, 5)
void fused_pass(const u16* __restrict__ P1, const u16* __restrict__ P2,
                const u16* __restrict__ y1, const u16* __restrict__ y2,
                float* __restrict__ out1, float* __restrict__ out2, int Mrows)
{
    __shared__ u32 lds[2][4096];   // 2 x 16 KB chunk buffers
    const int tid = threadIdx.x;
    const int w   = tid >> 6;
    const int l   = tid & 63;
    const int n0  = l & 15;
    const int hi  = l >> 4;
    const int wm  = w & 1;
    const int wk  = w >> 1;
    const int m0  = blockIdx.x * 64 + wm * 32;
    const int kbase0 = blockIdx.y * (CH * 64);

    // P1 B-fragments (block-constant): 2 m-tiles x 4 K-steps
    s16x8 bfrag[2][4];
    #pragma unroll
    for (int mt = 0; mt < 2; ++mt) {
        const uint4* ap = (const uint4*)(P1 + (size_t)(m0 + 16 * mt + n0) * 128);
        #pragma unroll
        for (int ki = 0; ki < 4; ++ki) bfrag[mt][ki] = frag_cast(ap[4 * ki + hi]);
    }

    // staging: per-wave 4 x 1KB loads; LDS linear, source col pre-XOR'd sigma.
    int gofs[4];
    #pragma unroll
    for (int i = 0; i < 4; ++i) {
        const int row = 16 * w + 4 * i + hi;
        gofs[i] = row * 128 + ((n0 ^ sigma(row)) << 3);
    }
    const u16* p2base = P2 + (size_t)kbase0 * 128;

    f32x4 acc1[2] = {{0.f,0.f,0.f,0.f},{0.f,0.f,0.f,0.f}};
    f32x4 acc2[2] = {{0.f,0.f,0.f,0.f},{0.f,0.f,0.f,0.f}};

    const int rowT0 = 32 * wk + 8 * (n0 >> 2) + (n0 & 3);   // rowperm base
    const size_t ybase = (size_t)(4 * wk + hi) * 128 + (size_t)n0 * 8;

    // prologue stage
    {
        #pragma unroll
        for (int i = 0; i < 4; ++i)
            g2l16((const u32*)(p2base + gofs[i]), &lds[0][w * 1024 + i * 256]);
    }
    __syncthreads();

    #pragma unroll 1
    for (int c = 0; c < CH; ++c) {
        if (c < CH - 1) {   // async stage next chunk into the other buffer
            const u16* src = p2base + (size_t)(c + 1) * 64 * 128;
            #pragma unroll
            for (int i = 0; i < 4; ++i)
                g2l16((const u32*)(src + gofs[i]), &lds[(c + 1) & 1][w * 1024 + i * 256]);
        }
        // y fragment loads issued early; inner MFMA + trig hide the L2 hit
        const int kbase = kbase0 + c * 64;
        const uint4 y1c = *(const uint4*)(y1 + (size_t)(kbase >> 3) * 128 + ybase);
        uint4 y2c;
        if (MODE == 1) y2c = *(const uint4*)(y2 + (size_t)(kbase >> 3) * 128 + ybase);

        const u32* buf = lds[c & 1];
        u32 cf0[4], sf0[4], cf1[4], sf1[4];
        #pragma unroll
        for (int T = 0; T < 2; ++T) {
            const int row = rowT0 + 4 * T;
            const int sg  = sigma(row);
            const u32* rb = buf + row * 64;
            uint4 af[4];
            #pragma unroll
            for (int ki = 0; ki < 4; ++ki)
                af[ki] = *(const uint4*)(rb + (((4 * ki + hi) ^ sg) << 2));
            f32x4 z0 = {0.f,0.f,0.f,0.f}, z1 = {0.f,0.f,0.f,0.f};
            #pragma unroll
            for (int ki = 0; ki < 4; ++ki) {
                z0 = __builtin_amdgcn_mfma_f32_16x16x32_bf16(frag_cast(af[ki]), bfrag[0][ki], z0, 0, 0, 0);
                z1 = __builtin_amdgcn_mfma_f32_16x16x32_bf16(frag_cast(af[ki]), bfrag[1][ki], z1, 0, 0, 0);
            }
            float c0[4], s0[4], c1[4], s1[4];
            #pragma unroll
            for (int r = 0; r < 4; ++r) {
                const float rv0 = __builtin_amdgcn_fractf(z0[r]);
                c0[r] = __builtin_amdgcn_cosf(rv0);
                s0[r] = __builtin_amdgcn_sinf(rv0);
                const float rv1 = __builtin_amdgcn_fractf(z1[r]);
                c1[r] = __builtin_amdgcn_cosf(rv1);
                s1[r] = __builtin_amdgcn_sinf(rv1);
            }
            cf0[2 * T + 0] = cvt_pk_bf16(c0[0], c0[1]);
            cf0[2 * T + 1] = cvt_pk_bf16(c0[2], c0[3]);
            sf0[2 * T + 0] = cvt_pk_bf16(s0[0], s0[1]);
            sf0[2 * T + 1] = cvt_pk_bf16(s0[2], s0[3]);
            cf1[2 * T + 0] = cvt_pk_bf16(c1[0], c1[1]);
            cf1[2 * T + 1] = cvt_pk_bf16(c1[2], c1[3]);
            sf1[2 * T + 0] = cvt_pk_bf16(s1[0], s1[1]);
            sf1[2 * T + 1] = cvt_pk_bf16(s1[2], s1[3]);
        }
        const s16x8 cfr0 = frag_cast(uint4{cf0[0], cf0[1], cf0[2], cf0[3]});
        const s16x8 sfr0 = frag_cast(uint4{sf0[0], sf0[1], sf0[2], sf0[3]});
        const s16x8 cfr1 = frag_cast(uint4{cf1[0], cf1[1], cf1[2], cf1[3]});
        const s16x8 sfr1 = frag_cast(uint4{sf1[0], sf1[1], sf1[2], sf1[3]});
        const s16x8 yf1 = frag_cast(y1c);
        if (MODE == 0) {
            acc1[0] = __builtin_amdgcn_mfma_f32_16x16x32_bf16(cfr0, yf1, acc1[0], 0, 0, 0);
            acc2[0] = __builtin_amdgcn_mfma_f32_16x16x32_bf16(sfr0, yf1, acc2[0], 0, 0, 0);
            acc1[1] = __builtin_amdgcn_mfma_f32_16x16x32_bf16(cfr1, yf1, acc1[1], 0, 0, 0);
            acc2[1] = __builtin_amdgcn_mfma_f32_16x16x32_bf16(sfr1, yf1, acc2[1], 0, 0, 0);
        } else {
            const s16x8 yf2 = frag_cast(y2c);
            acc1[0] = __builtin_amdgcn_mfma_f32_16x16x32_bf16(cfr0, yf1, acc1[0], 0, 0, 0);
            acc1[0] = __builtin_amdgcn_mfma_f32_16x16x32_bf16(sfr0, yf2, acc1[0], 0, 0, 0);
            acc1[1] = __builtin_amdgcn_mfma_f32_16x16x32_bf16(cfr1, yf1, acc1[1], 0, 0, 0);
            acc1[1] = __builtin_amdgcn_mfma_f32_16x16x32_bf16(sfr1, yf2, acc1[1], 0, 0, 0);
        }
        __syncthreads();   // drains stage(c+1) + LDS reads; safe buffer flip
    }

    // ---- epilogue: cross-wk reduction via LDS, then global write ----
    float* red = reinterpret_cast<float*>(&lds[0][0]);   // 8 KB used
    if (wk == 1) {
        #pragma unroll
        for (int mt = 0; mt < 2; ++mt)
            #pragma unroll
            for (int r = 0; r < 4; ++r) {
                red[((wm * 2 + mt) * 16 + 4 * hi + r) * 16 + n0] = acc1[mt][r];
                if (MODE == 0)
                    red[1024 + ((wm * 2 + mt) * 16 + 4 * hi + r) * 16 + n0] = acc2[mt][r];
            }
    }
    __syncthreads();
    if (wk == 0) {
        float* o1 = out1 + (size_t)blockIdx.y * Mrows * 16;
        float* o2 = out2 + (size_t)blockIdx.y * Mrows * 16;
        #pragma unroll
        for (int mt = 0; mt < 2; ++mt)
            #pragma unroll
            for (int r = 0; r < 4; ++r) {
                const int orow = m0 + 16 * mt + 4 * hi + r;
                const float v1 = acc1[mt][r] + red[((wm * 2 + mt) * 16 + 4 * hi + r) * 16 + n0];
                if (MODE == 0) {
                    o1[orow * 16 + n0] = v1;
                    o2[orow * 16 + n0] = acc2[mt][r] + red[1024 + ((wm * 2 + mt) * 16 + 4 * hi + r) * 16 + n0];
                } else {
                    o1[(size_t)n0 * Mrows + orow] = v1;   // [b][m] for coalesced reduce
                }
            }
    }
}

// state = (sum of 8 partials)/128 -> bf16 packed B-frag layout (re, im)
__global__ void finishA(const float* __restrict__ ar, const float* __restrict__ ai,
                        u16* __restrict__ pr, u16* __restrict__ pi)
{
    const int i = blockIdx.x * 256 + threadIdx.x;
    float sr = 0.f, si = 0.f;
    #pragma unroll
    for (int p = 0; p < 8; ++p) {
        sr += ar[(size_t)p * (D_DIM * 16) + i];
        si += ai[(size_t)p * (D_DIM * 16) + i];
    }
    const int d = i >> 4, b = i & 15;
    const int pidx = ((d >> 3) << 7) + (b << 3) + (d & 7);
    pr[pidx] = bf16bits(sr * 0.0078125f);
    pi[pidx] = bf16bits(si * 0.0078125f);
}

// out_state = (sum/128) * phi_v -> bf16 packed
__global__ void finishC(const float* __restrict__ ar, const float* __restrict__ ai,
                        const float* __restrict__ pvr, const float* __restrict__ pvi,
                        u16* __restrict__ pr, u16* __restrict__ pi)
{
    const int i = blockIdx.x * 256 + threadIdx.x;
    float sr = 0.f, si = 0.f;
    #pragma unroll
    for (int p = 0; p < 8; ++p) {
        sr += ar[(size_t)p * (D_DIM * 16) + i];
        si += ai[(size_t)p * (D_DIM * 16) + i];
    }
    const float nr = sr * 0.0078125f, ni = si * 0.0078125f;
    const float xr = nr * pvr[i] - ni * pvi[i];
    const float xi = nr * pvi[i] + ni * pvr[i];
    const int d = i >> 4, b = i & 15;
    const int pidx = ((d >> 3) << 7) + (b << 3) + (d & 7);
    pr[pidx] = bf16bits(xr);
    pi[pidx] = bf16bits(xi);
}

// sum 32 transposed score partials [b][s] -> scT[b][s] f32 (incl 1/sqrt(D)).
// 256 blocks, fully coalesced.
__global__ void reduce_scores(const float* __restrict__ acc, float* __restrict__ scT)
{
    const int i = blockIdx.x * 256 + threadIdx.x;   // 65536 = B*S
    float s = 0.f;
    #pragma unroll
    for (int p = 0; p < 32; ++p)
        s += acc[(size_t)p * (S_DIM * 16) + i];
    scT[i] = s * 0.0078125f;
}

// Column softmax over s (4096) per b, from b-major scT (coalesced float4).
// OUT=0: bf16 packed weights. OUT=1: f32 result [s][b].
template<int OUT>
__global__ void softmax_col(const float* __restrict__ scT, u16* __restrict__ wp,
                            float* __restrict__ outp)
{
    const int b = blockIdx.x;
    const int tid = threadIdx.x;
    __shared__ float red[4];
    const float4* src = (const float4*)(scT + (size_t)b * S_DIM);
    float4 x[4];
    float m = -1e30f;
    #pragma unroll
    for (int j = 0; j < 4; ++j) {
        x[j] = src[j * 256 + tid];
        m = fmaxf(fmaxf(m, fmaxf(x[j].x, x[j].y)), fmaxf(x[j].z, x[j].w));
    }
    #pragma unroll
    for (int off = 1; off < 64; off <<= 1) m = fmaxf(m, __shfl_xor(m, off, 64));
    if ((tid & 63) == 0) red[tid >> 6] = m;
    __syncthreads();
    m = fmaxf(fmaxf(red[0], red[1]), fmaxf(red[2], red[3]));
    float sum = 0.f;
    #pragma unroll
    for (int j = 0; j < 4; ++j) {
        x[j].x = expf(x[j].x - m); x[j].y = expf(x[j].y - m);
        x[j].z = expf(x[j].z - m); x[j].w = expf(x[j].w - m);
        sum += x[j].x + x[j].y + x[j].z + x[j].w;
    }
    #pragma unroll
    for (int off = 1; off < 64; off <<= 1) sum += __shfl_xor(sum, off, 64);
    __syncthreads();
    if ((tid & 63) == 0) red[tid >> 6] = sum;
    __syncthreads();
    const float inv = 1.0f / (red[0] + red[1] + red[2] + red[3]);
    #pragma unroll
    for (int j = 0; j < 4; ++j) {
        const int s4 = (j * 256 + tid) * 4;
        float v4[4] = {x[j].x * inv, x[j].y * inv, x[j].z * inv, x[j].w * inv};
        #pragma unroll
        for (int q = 0; q < 4; ++q) {
            const int s = s4 + q;
            if (OUT == 0) wp[((s >> 3) << 7) + (b << 3) + (s & 7)] = bf16bits(v4[q]);
            else          outp[s * 16 + b] = v4[q];
        }
    }
}

// ---------------------------------------------------------------------------
extern "C" void kernel_launch(void* const* d_in, const int* in_sizes, int n_in,
                              void* d_out, int out_size, void* d_ws, size_t ws_size,
                              hipStream_t stream)
{
    const float* obs = (const float*)d_in[0];
    const float* act = (const float*)d_in[1];
    const float* Q   = (const float*)d_in[2];
    const float* V   = (const float*)d_in[3];
    const float* W   = (const float*)d_in[4];
    float* out = (float*)d_out;
    char* ws = (char*)d_ws;

    // workspace layout (bytes)
    u16*   Wb     = (u16*)  (ws + 0);          // 4 MB   bf16 W/(2pi) [D][128]
    u16*   QT     = (u16*)  (ws + 4194304);    // 1 MB   bf16 Q^T [S][128]
    u16*   obsP   = (u16*)  (ws + 5242880);    // 128 KB packed obs
    u16*   wP     = (u16*)  (ws + 5373952);    // 128 KB packed weights
    u16*   stRe   = (u16*)  (ws + 5505024);    // 512 KB packed state re
    u16*   stIm   = (u16*)  (ws + 6029312);    // 512 KB packed state im
    u16*   osRe   = (u16*)  (ws + 6553600);    // 512 KB packed out_state re
    u16*   osIm   = (u16*)  (ws + 7077888);    // 512 KB packed out_state im
    float* pvR    = (float*)(ws + 7602176);    // 1 MB   phi_v re (incl 1/128)
    float* pvI    = (float*)(ws + 8650752);    // 1 MB   phi_v im
    float* vv     = (float*)(ws + 9699328);    // 8 KB   v[k][b]
    float* partR  = (float*)(ws + 9707520);    // 8 MB (8 splits x 1 MB)
    float* partI  = (float*)(ws + 18096128);   // 8 MB
    float* partS  = (float*)(ws + 9707520);    // alias of partR, 32 x 256 KB
    float* scT    = (float*)(ws + 18096128);   // alias of partI, 256 KB

    prep_kernel<<<1024, 256, 0, stream>>>(W, Q, obs, Wb, QT, obsP);
    kv_kernel<<<64, 256, 0, stream>>>(V, act, vv);
    phiv_kernel<<<1024, 256, 0, stream>>>(W, vv, pvR, pvI);

    // pass A: state = phi @ obs^T      (M=D, 8 K-splits over S, 2048 blocks)
    fused_pass<0><<<dim3(256, 8), 256, 0, stream>>>(Wb, QT, obsP, obsP, partR, partI, D_DIM);
    finishA<<<1024, 256, 0, stream>>>(partR, partI, stRe, stIm);

    // pass B: scores = Re(phi^H @ state)   (M=S, 32 K-splits over D, 2048 blocks)
    fused_pass<1><<<dim3(64, 32), 256, 0, stream>>>(QT, Wb, stRe, stIm, partS, partS, S_DIM);
    reduce_scores<<<256, 256, 0, stream>>>(partS, scT);
    softmax_col<0><<<16, 256, 0, stream>>>(scT, wP, nullptr);

    // pass C: new_state = phi @ weights ; out_state = new_state * phi_v
    fused_pass<0><<<dim3(256, 8), 256, 0, stream>>>(Wb, QT, wP, wP, partR, partI, D_DIM);
    finishC<<<1024, 256, 0, stream>>>(partR, partI, pvR, pvI, osRe, osIm);

    // pass D: out = softmax(Re(phi^H @ out_state))
    fused_pass<1><<<dim3(64, 32), 256, 0, stream>>>(QT, Wb, osRe, osIm, partS, partS, S_DIM);
    reduce_scores<<<256, 256, 0, stream>>>(partS, scT);
    softmax_col<1><<<16, 256, 0, stream>>>(scT, nullptr, out);
}

// Round 10
// 226.737 us; speedup vs baseline: 1.0840x; 1.0840x over previous
//
#include <hip/hip_runtime.h>
#include <hip/hip_bf16.h>
#include <cstdint>
#include <cstddef>

// Problem constants
#define D_DIM 16384   // random feature dim
#define S_DIM 4096    // n_states
#define A_DIM 512     // n_actions
#define K_DIM 128     // state_dim
#define B_DIM 16      // batch
#define CH    16      // chunks (of 64 kc rows) per fused block

#define INV2PI 0.15915494309189535f

typedef float f32x4 __attribute__((ext_vector_type(4)));
typedef short s16x8 __attribute__((ext_vector_type(8)));
typedef unsigned short u16;
typedef unsigned int   u32;

__device__ __forceinline__ u16 bf16bits(float x) {
    return __builtin_bit_cast(u16, (__bf16)x);
}
__device__ __forceinline__ s16x8 frag_cast(uint4 u) {
    return __builtin_bit_cast(s16x8, u);
}
// D.lo = bf16(lo), D.hi = bf16(hi)
__device__ __forceinline__ u32 cvt_pk_bf16(float lo, float hi) {
    u32 r;
    asm("v_cvt_pk_bf16_f32 %0, %1, %2" : "=v"(r) : "v"(lo), "v"(hi));
    return r;
}
// LDS 16B-chunk XOR swizzle (balanced: every bank serves exactly 8 u32 per
// ds_read_b128). Applied on BOTH the staging source and the read (rule #21).
__device__ __forceinline__ int sigma(int row) {
    return (row & 7) ^ ((row >> 1) & 4);
}
// async global->LDS 16B: LDS dest = wave-uniform base + lane*16 (HW rule)
__device__ __forceinline__ void g2l16(const u32* g, u32* l) {
    __builtin_amdgcn_global_load_lds((const __attribute__((address_space(1))) u32*)g,
                                     (__attribute__((address_space(3))) u32*)l, 16, 0, 0);
}

// ---------------------------------------------------------------------------
// Merged prep (grid 1152, block-range dispatch):
//  blocks [0,1024):    W*(1/2pi) -> bf16 Wb [D][128]; obs -> packed obsP
//  blocks [1024,1088): v[k][b] = sum_a V[k][a]*act[b][a]
//  blocks [1088,1152): Q -> QT bf16 [S][128] via LDS-tiled 32x256 transpose
// ---------------------------------------------------------------------------
__global__ __launch_bounds__(256, 4)
void prep_kernel(const float* __restrict__ W, const float* __restrict__ Q,
                 const float* __restrict__ obs, const float* __restrict__ V,
                 const float* __restrict__ act,
                 u16* __restrict__ Wb, u16* __restrict__ QT,
                 u16* __restrict__ obsP, float* __restrict__ vv)
{
    __shared__ float tsp[32][257];   // transpose tile (padded, conflict-free cols)
    const int tid = threadIdx.x;
    if (blockIdx.x < 1024) {
        const int i0 = blockIdx.x * 256 + tid;
        const int stride = 1024 * 256;
        const float4* wp = (const float4*)W;
        for (int i = i0; i < D_DIM * 16; i += stride) {
            float4 a = wp[2 * i], b = wp[2 * i + 1];
            uint4 o;
            o.x = cvt_pk_bf16(a.x * INV2PI, a.y * INV2PI);
            o.y = cvt_pk_bf16(a.z * INV2PI, a.w * INV2PI);
            o.z = cvt_pk_bf16(b.x * INV2PI, b.y * INV2PI);
            o.w = cvt_pk_bf16(b.z * INV2PI, b.w * INV2PI);
            ((uint4*)Wb)[i] = o;
        }
        for (int i = i0; i < B_DIM * S_DIM; i += stride) {   // i = b*4096 + s
            int b = i >> 12, s = i & 4095;
            obsP[((s >> 3) << 7) + (b << 3) + (s & 7)] = bf16bits(obs[i]);
        }
    } else if (blockIdx.x < 1088) {
        const int out = (blockIdx.x - 1024) * 32 + (tid >> 3);   // 2048 outputs
        const int part = tid & 7;
        const int k = out >> 4, b = out & 15;
        const float4* vp = (const float4*)(V + (size_t)k * A_DIM);
        const float4* ap = (const float4*)(act + (size_t)b * A_DIM);
        float s = 0.f;
        #pragma unroll
        for (int q = part * 16; q < part * 16 + 16; ++q) {
            float4 x = vp[q], y = ap[q];
            s += x.x * y.x + x.y * y.y + x.z * y.z + x.w * y.w;
        }
        s += __shfl_xor(s, 1, 64);
        s += __shfl_xor(s, 2, 64);
        s += __shfl_xor(s, 4, 64);
        if (part == 0) vv[out] = s;
    } else {
        const int idx = blockIdx.x - 1088;        // 64 tiles: 4 k-tiles x 16 s-tiles
        const int k0 = (idx & 3) * 32;
        const int s0 = (idx >> 2) * 256;
        #pragma unroll 4
        for (int r = 0; r < 32; ++r)              // coalesced reads of Q rows
            tsp[r][tid] = Q[(size_t)(k0 + r) * S_DIM + s0 + tid];
        __syncthreads();
        u16* dst = QT + (size_t)(s0 + tid) * 128 + k0;   // full 64B line per thread
        #pragma unroll
        for (int j = 0; j < 4; ++j) {
            uint4 o;
            o.x = cvt_pk_bf16(tsp[8 * j + 0][tid], tsp[8 * j + 1][tid]);
            o.y = cvt_pk_bf16(tsp[8 * j + 2][tid], tsp[8 * j + 3][tid]);
            o.z = cvt_pk_bf16(tsp[8 * j + 4][tid], tsp[8 * j + 5][tid]);
            o.w = cvt_pk_bf16(tsp[8 * j + 6][tid], tsp[8 * j + 7][tid]);
            *(uint4*)(dst + 8 * j) = o;
        }
    }
}

// phi_v[d][b] = exp(i*(W@v)[d][b]) / 128 — LDS-tiled (16 d-rows x 16 b per block).
// W tile + transposed v both in padded LDS; fast fract+v_cos trig (phase err
// ~3e-6 rad << 0.02 score budget).
__global__ __launch_bounds__(256, 4)
void phiv_kernel(const float* __restrict__ W, const float* __restrict__ v,
                 float* __restrict__ pvr, float* __restrict__ pvi)
{
    __shared__ float wl[16][132];    // padded: float4-aligned rows, spread banks
    __shared__ float svT[16][132];
    const int tid = threadIdx.x;
    const int d0 = blockIdx.x * 16;
    for (int j = tid; j < 2048; j += 256)
        wl[j >> 7][j & 127] = W[(size_t)d0 * 128 + j];
    for (int j = tid; j < 2048; j += 256)
        svT[j & 15][j >> 4] = v[j];             // v[k][b] -> svT[b][k]
    __syncthreads();
    const int dd = tid >> 4, b = tid & 15;
    float z = 0.f;
    #pragma unroll
    for (int q = 0; q < 32; ++q) {
        const float4 w4 = *(const float4*)&wl[dd][4 * q];
        const float4 s4 = *(const float4*)&svT[b][4 * q];
        z += w4.x * s4.x + w4.y * s4.y + w4.z * s4.z + w4.w * s4.w;
    }
    const float rv = __builtin_amdgcn_fractf(z * INV2PI);
    const int i = (d0 + dd) * 16 + b;
    pvr[i] = __builtin_amdgcn_cosf(rv) * 0.0078125f;
    pvi[i] = __builtin_amdgcn_sinf(rv) * 0.0078125f;
}

// ---------------------------------------------------------------------------
// Fused phi-GEMM pass — byte-identical to the R6 best (227.6 us total).
// 2-phase LDS-staged, CH=16 chunks of 64 kc rows, y register double-buffer.
//  MODE 0: out1 = cos@y1 ; out2 = sin@y1   (A, C; [m][b] partials)
//  MODE 1: out1 = cos@y1 + sin@y2          (B, D; [b][m] partials)
// ---------------------------------------------------------------------------
template<int MODE>
__global__ __launch_bounds__(256, 4)
void fused_pass(const u16* __restrict__ P1, const u16* __restrict__ P2,
                const u16* __restrict__ y1, const u16* __restrict__ y2,
                float* __restrict__ out1, float* __restrict__ out2, int Mrows)
{
    __shared__ u32 lds[2][4096];   // 2 x 16 KB chunk buffers
    const int tid = threadIdx.x;
    const int w   = tid >> 6;
    const int l   = tid & 63;
    const int n0  = l & 15;
    const int hi  = l >> 4;
    const int wm  = w & 1;
    const int wk  = w >> 1;
    const int m0  = blockIdx.x * 64 + wm * 32;
    const int kbase0 = blockIdx.y * (CH * 64);

    s16x8 bfrag[2][4];
    #pragma unroll
    for (int mt = 0; mt < 2; ++mt) {
        const uint4* ap = (const uint4*)(P1 + (size_t)(m0 + 16 * mt + n0) * 128);
        #pragma unroll
        for (int ki = 0; ki < 4; ++ki) bfrag[mt][ki] = frag_cast(ap[4 * ki + hi]);
    }

    int gofs[4];
    #pragma unroll
    for (int i = 0; i < 4; ++i) {
        const int row = 16 * w + 4 * i + (l >> 4);
        gofs[i] = row * 128 + (((l & 15) ^ sigma(row)) << 3);
    }
    const u16* p2base = P2 + (size_t)kbase0 * 128;

    f32x4 acc1[2] = {{0.f,0.f,0.f,0.f},{0.f,0.f,0.f,0.f}};
    f32x4 acc2[2] = {{0.f,0.f,0.f,0.f},{0.f,0.f,0.f,0.f}};

    const int rowT0 = 32 * wk + 8 * (n0 >> 2) + (n0 & 3);   // rowperm base

    const size_t ybase = (size_t)(4 * wk + hi) * 128 + (size_t)n0 * 8;
    #define YLD(Y, c) (*(const uint4*)((Y) + (size_t)((kbase0 + (c) * 64) >> 3) * 128 + ybase))

    {
        #pragma unroll
        for (int i = 0; i < 4; ++i)
            g2l16((const u32*)(p2base + gofs[i]), &lds[0][w * 1024 + i * 256]);
    }
    uint4 y1c = YLD(y1, 0);
    uint4 y2c;
    if (MODE == 1) y2c = YLD(y2, 0);
    __syncthreads();

    #pragma unroll 1
    for (int c = 0; c < CH; ++c) {
        uint4 y1n, y2n;
        if (c < CH - 1) {   // async stage next chunk + prefetch next y
            const u16* src = p2base + (size_t)(c + 1) * 64 * 128;
            #pragma unroll
            for (int i = 0; i < 4; ++i)
                g2l16((const u32*)(src + gofs[i]), &lds[(c + 1) & 1][w * 1024 + i * 256]);
            y1n = YLD(y1, c + 1);
            if (MODE == 1) y2n = YLD(y2, c + 1);
        }
        const u32* buf = lds[c & 1];
        u32 cf0[4], sf0[4], cf1[4], sf1[4];
        #pragma unroll
        for (int T = 0; T < 2; ++T) {
            const int row = rowT0 + 4 * T;
            const int sg  = sigma(row);
            const u32* rb = buf + row * 64;
            uint4 af[4];
            #pragma unroll
            for (int ki = 0; ki < 4; ++ki)
                af[ki] = *(const uint4*)(rb + (((4 * ki + hi) ^ sg) << 2));
            f32x4 z0 = {0.f,0.f,0.f,0.f}, z1 = {0.f,0.f,0.f,0.f};
            #pragma unroll
            for (int ki = 0; ki < 4; ++ki) {
                z0 = __builtin_amdgcn_mfma_f32_16x16x32_bf16(frag_cast(af[ki]), bfrag[0][ki], z0, 0, 0, 0);
                z1 = __builtin_amdgcn_mfma_f32_16x16x32_bf16(frag_cast(af[ki]), bfrag[1][ki], z1, 0, 0, 0);
            }
            float c0[4], s0[4], c1[4], s1[4];
            #pragma unroll
            for (int r = 0; r < 4; ++r) {
                const float rv0 = __builtin_amdgcn_fractf(z0[r]);
                c0[r] = __builtin_amdgcn_cosf(rv0);
                s0[r] = __builtin_amdgcn_sinf(rv0);
                const float rv1 = __builtin_amdgcn_fractf(z1[r]);
                c1[r] = __builtin_amdgcn_cosf(rv1);
                s1[r] = __builtin_amdgcn_sinf(rv1);
            }
            cf0[2 * T + 0] = cvt_pk_bf16(c0[0], c0[1]);
            cf0[2 * T + 1] = cvt_pk_bf16(c0[2], c0[3]);
            sf0[2 * T + 0] = cvt_pk_bf16(s0[0], s0[1]);
            sf0[2 * T + 1] = cvt_pk_bf16(s0[2], s0[3]);
            cf1[2 * T + 0] = cvt_pk_bf16(c1[0], c1[1]);
            cf1[2 * T + 1] = cvt_pk_bf16(c1[2], c1[3]);
            sf1[2 * T + 0] = cvt_pk_bf16(s1[0], s1[1]);
            sf1[2 * T + 1] = cvt_pk_bf16(s1[2], s1[3]);
        }
        const s16x8 cfr0 = frag_cast(uint4{cf0[0], cf0[1], cf0[2], cf0[3]});
        const s16x8 sfr0 = frag_cast(uint4{sf0[0], sf0[1], sf0[2], sf0[3]});
        const s16x8 cfr1 = frag_cast(uint4{cf1[0], cf1[1], cf1[2], cf1[3]});
        const s16x8 sfr1 = frag_cast(uint4{sf1[0], sf1[1], sf1[2], sf1[3]});
        const s16x8 yf1 = frag_cast(y1c);
        if (MODE == 0) {
            acc1[0] = __builtin_amdgcn_mfma_f32_16x16x32_bf16(cfr0, yf1, acc1[0], 0, 0, 0);
            acc2[0] = __builtin_amdgcn_mfma_f32_16x16x32_bf16(sfr0, yf1, acc2[0], 0, 0, 0);
            acc1[1] = __builtin_amdgcn_mfma_f32_16x16x32_bf16(cfr1, yf1, acc1[1], 0, 0, 0);
            acc2[1] = __builtin_amdgcn_mfma_f32_16x16x32_bf16(sfr1, yf1, acc2[1], 0, 0, 0);
        } else {
            const s16x8 yf2 = frag_cast(y2c);
            acc1[0] = __builtin_amdgcn_mfma_f32_16x16x32_bf16(cfr0, yf1, acc1[0], 0, 0, 0);
            acc1[0] = __builtin_amdgcn_mfma_f32_16x16x32_bf16(sfr0, yf2, acc1[0], 0, 0, 0);
            acc1[1] = __builtin_amdgcn_mfma_f32_16x16x32_bf16(cfr1, yf1, acc1[1], 0, 0, 0);
            acc1[1] = __builtin_amdgcn_mfma_f32_16x16x32_bf16(sfr1, yf2, acc1[1], 0, 0, 0);
        }
        __syncthreads();   // drains stage(c+1) + LDS reads; safe buffer flip
        if (c < CH - 1) {
            y1c = y1n;
            if (MODE == 1) y2c = y2n;
        }
    }
    #undef YLD

    // ---- epilogue: cross-wk reduction via LDS, then global write ----
    float* red = reinterpret_cast<float*>(&lds[0][0]);   // 8 KB used
    if (wk == 1) {
        #pragma unroll
        for (int mt = 0; mt < 2; ++mt)
            #pragma unroll
            for (int r = 0; r < 4; ++r) {
                red[((wm * 2 + mt) * 16 + 4 * hi + r) * 16 + n0] = acc1[mt][r];
                if (MODE == 0)
                    red[1024 + ((wm * 2 + mt) * 16 + 4 * hi + r) * 16 + n0] = acc2[mt][r];
            }
    }
    __syncthreads();
    if (wk == 0) {
        float* o1 = out1 + (size_t)blockIdx.y * Mrows * 16;
        float* o2 = out2 + (size_t)blockIdx.y * Mrows * 16;
        #pragma unroll
        for (int mt = 0; mt < 2; ++mt)
            #pragma unroll
            for (int r = 0; r < 4; ++r) {
                const int orow = m0 + 16 * mt + 4 * hi + r;
                const float v1 = acc1[mt][r] + red[((wm * 2 + mt) * 16 + 4 * hi + r) * 16 + n0];
                if (MODE == 0) {
                    o1[orow * 16 + n0] = v1;
                    o2[orow * 16 + n0] = acc2[mt][r] + red[1024 + ((wm * 2 + mt) * 16 + 4 * hi + r) * 16 + n0];
                } else {
                    o1[(size_t)n0 * Mrows + orow] = v1;   // [b][m] for coalesced reduce
                }
            }
    }
}

// state = (sum of 4 partials)/128 -> bf16 packed B-frag layout (re, im)
__global__ void finishA(const float* __restrict__ ar, const float* __restrict__ ai,
                        u16* __restrict__ pr, u16* __restrict__ pi)
{
    const int i = blockIdx.x * 256 + threadIdx.x;
    float sr = 0.f, si = 0.f;
    #pragma unroll
    for (int p = 0; p < 4; ++p) {
        sr += ar[(size_t)p * (D_DIM * 16) + i];
        si += ai[(size_t)p * (D_DIM * 16) + i];
    }
    const int d = i >> 4, b = i & 15;
    const int pidx = ((d >> 3) << 7) + (b << 3) + (d & 7);
    pr[pidx] = bf16bits(sr * 0.0078125f);
    pi[pidx] = bf16bits(si * 0.0078125f);
}

// out_state = (sum/128) * phi_v -> bf16 packed
__global__ void finishC(const float* __restrict__ ar, const float* __restrict__ ai,
                        const float* __restrict__ pvr, const float* __restrict__ pvi,
                        u16* __restrict__ pr, u16* __restrict__ pi)
{
    const int i = blockIdx.x * 256 + threadIdx.x;
    float sr = 0.f, si = 0.f;
    #pragma unroll
    for (int p = 0; p < 4; ++p) {
        sr += ar[(size_t)p * (D_DIM * 16) + i];
        si += ai[(size_t)p * (D_DIM * 16) + i];
    }
    const float nr = sr * 0.0078125f, ni = si * 0.0078125f;
    const float xr = nr * pvr[i] - ni * pvi[i];
    const float xi = nr * pvi[i] + ni * pvr[i];
    const int d = i >> 4, b = i & 15;
    const int pidx = ((d >> 3) << 7) + (b << 3) + (d & 7);
    pr[pidx] = bf16bits(xr);
    pi[pidx] = bf16bits(xi);
}

// Column softmax over s (4096) per b, fused 16-partial reduction.
// OUT=0: bf16 packed weights. OUT=1: f32 result [s][b].
template<int OUT>
__global__ void softmax_col(const float* __restrict__ acc, u16* __restrict__ wp,
                            float* __restrict__ outp)
{
    const int b = blockIdx.x;
    const int tid = threadIdx.x;
    __shared__ float red[4];
    float4 x[4];
    float m = -1e30f;
    #pragma unroll
    for (int j = 0; j < 4; ++j) {
        float4 s4 = {0.f, 0.f, 0.f, 0.f};
        #pragma unroll
        for (int p = 0; p < 16; ++p) {
            const float4 t = *(const float4*)(acc + (size_t)p * (S_DIM * 16)
                                              + (size_t)b * S_DIM + (j * 256 + tid) * 4);
            s4.x += t.x; s4.y += t.y; s4.z += t.z; s4.w += t.w;
        }
        x[j].x = s4.x * 0.0078125f; x[j].y = s4.y * 0.0078125f;
        x[j].z = s4.z * 0.0078125f; x[j].w = s4.w * 0.0078125f;
        m = fmaxf(fmaxf(m, fmaxf(x[j].x, x[j].y)), fmaxf(x[j].z, x[j].w));
    }
    #pragma unroll
    for (int off = 1; off < 64; off <<= 1) m = fmaxf(m, __shfl_xor(m, off, 64));
    if ((tid & 63) == 0) red[tid >> 6] = m;
    __syncthreads();
    m = fmaxf(fmaxf(red[0], red[1]), fmaxf(red[2], red[3]));
    float sum = 0.f;
    #pragma unroll
    for (int j = 0; j < 4; ++j) {
        x[j].x = expf(x[j].x - m); x[j].y = expf(x[j].y - m);
        x[j].z = expf(x[j].z - m); x[j].w = expf(x[j].w - m);
        sum += x[j].x + x[j].y + x[j].z + x[j].w;
    }
    #pragma unroll
    for (int off = 1; off < 64; off <<= 1) sum += __shfl_xor(sum, off, 64);
    __syncthreads();
    if ((tid & 63) == 0) red[tid >> 6] = sum;
    __syncthreads();
    const float inv = 1.0f / (red[0] + red[1] + red[2] + red[3]);
    #pragma unroll
    for (int j = 0; j < 4; ++j) {
        const int s4i = (j * 256 + tid) * 4;
        float v4[4] = {x[j].x * inv, x[j].y * inv, x[j].z * inv, x[j].w * inv};
        #pragma unroll
        for (int q = 0; q < 4; ++q) {
            const int s = s4i + q;
            if (OUT == 0) wp[((s >> 3) << 7) + (b << 3) + (s & 7)] = bf16bits(v4[q]);
            else          outp[s * 16 + b] = v4[q];
        }
    }
}

// ---------------------------------------------------------------------------
extern "C" void kernel_launch(void* const* d_in, const int* in_sizes, int n_in,
                              void* d_out, int out_size, void* d_ws, size_t ws_size,
                              hipStream_t stream)
{
    const float* obs = (const float*)d_in[0];
    const float* act = (const float*)d_in[1];
    const float* Q   = (const float*)d_in[2];
    const float* V   = (const float*)d_in[3];
    const float* W   = (const float*)d_in[4];
    float* out = (float*)d_out;
    char* ws = (char*)d_ws;

    // workspace layout (bytes)
    u16*   Wb     = (u16*)  (ws + 0);          // 4 MB   bf16 W/(2pi) [D][128]
    u16*   QT     = (u16*)  (ws + 4194304);    // 1 MB   bf16 Q^T [S][128]
    u16*   obsP   = (u16*)  (ws + 5242880);    // 128 KB packed obs
    u16*   wP     = (u16*)  (ws + 5373952);    // 128 KB packed weights
    u16*   stRe   = (u16*)  (ws + 5505024);    // 512 KB packed state re
    u16*   stIm   = (u16*)  (ws + 6029312);    // 512 KB packed state im
    u16*   osRe   = (u16*)  (ws + 6553600);    // 512 KB packed out_state re
    u16*   osIm   = (u16*)  (ws + 7077888);    // 512 KB packed out_state im
    float* pvR    = (float*)(ws + 7602176);    // 1 MB   phi_v re (incl 1/128)
    float* pvI    = (float*)(ws + 8650752);    // 1 MB   phi_v im
    float* vv     = (float*)(ws + 9699328);    // 8 KB   v[k][b]
    float* partR  = (float*)(ws + 9707520);    // 8 MB (4 splits x 1 MB used)
    float* partI  = (float*)(ws + 18096128);   // 8 MB
    float* partS  = (float*)(ws + 9707520);    // alias of partR (disjoint lifetime), 16 x 256 KB

    prep_kernel<<<1152, 256, 0, stream>>>(W, Q, obs, V, act, Wb, QT, obsP, vv);
    phiv_kernel<<<1024, 256, 0, stream>>>(W, vv, pvR, pvI);

    // pass A: state = phi @ obs^T      (M=D, 4 K-splits over S)
    fused_pass<0><<<dim3(256, 4), 256, 0, stream>>>(Wb, QT, obsP, obsP, partR, partI, D_DIM);
    finishA<<<1024, 256, 0, stream>>>(partR, partI, stRe, stIm);

    // pass B: scores = Re(phi^H @ state)   (M=S, 16 K-splits over D)
    fused_pass<1><<<dim3(64, 16), 256, 0, stream>>>(QT, Wb, stRe, stIm, partS, partS, S_DIM);
    softmax_col<0><<<16, 256, 0, stream>>>(partS, wP, nullptr);

    // pass C: new_state = phi @ weights ; out_state = new_state * phi_v
    fused_pass<0><<<dim3(256, 4), 256, 0, stream>>>(Wb, QT, wP, wP, partR, partI, D_DIM);
    finishC<<<1024, 256, 0, stream>>>(partR, partI, pvR, pvI, osRe, osIm);

    // pass D: out = softmax(Re(phi^H @ out_state))
    fused_pass<1><<<dim3(64, 16), 256, 0, stream>>>(QT, Wb, osRe, osIm, partS, partS, S_DIM);
    softmax_col<1><<<16, 256, 0, stream>>>(partS, nullptr, out);
}